// Round 3
// baseline (96.876 us; speedup 1.0000x reference)
//
#include <hip/hip_runtime.h>

#define GRID_N 100
#define T_LEN 2048
#define B_LEN 4096
#define D_LEN 2
#define NBLOCKS 2048
#define NTHREADS (NBLOCKS * 256)      // 524288
#define UNROLL 8
// n4 = B*T*D/4 = 4,194,304 = NTHREADS * UNROLL exactly (no tail)

__device__ __forceinline__ float w2_at(const float* __restrict__ traj2,
                                       const float* __restrict__ gt, int t) {
    float lat = traj2[2 * t + 0];
    float lon = traj2[2 * t + 1];
    int lat_g = (int)floorf((lat + 1.0f) * 50.0f);
    lat_g = min(max(lat_g, 0), GRID_N - 1);
    int lon_g = (int)floorf((lon + 1.0f) * 50.0f);
    lon_g = min(max(lon_g, 0), GRID_N - 1);
    return gt[lat_g * GRID_N + lon_g] * 0.0001f + 1.0f;
}

__global__ void __launch_bounds__(256) fused_loss_kernel(
        const float4* __restrict__ t1,
        const float4* __restrict__ t2,
        const float* __restrict__ traj2s,
        const float* __restrict__ grid_table,
        float* __restrict__ partials,
        unsigned int* __restrict__ counter,
        float* __restrict__ out,
        float scale) {
    const int tid = blockIdx.x * 256 + threadIdx.x;

    // Weight gather first: its dependent-load chain (traj2 -> idx -> table)
    // overlaps the bulk streaming loads below.
    const int t0 = 2 * (tid & (T_LEN * D_LEN / 4 - 1));
    const float wA = w2_at(traj2s, grid_table, t0);
    const float wB = w2_at(traj2s, grid_table, t0 + 1);

    // Bulk load phase: 16 float4 loads per thread
    float4 a[UNROLL], b[UNROLL];
    #pragma unroll
    for (int u = 0; u < UNROLL; ++u) {
        int j = tid + u * NTHREADS;
        a[u] = t1[j];
        b[u] = t2[j];
    }

    float accA = 0.0f, accB = 0.0f;
    #pragma unroll
    for (int u = 0; u < UNROLL; ++u) {
        float d0 = a[u].x - b[u].x;
        float d1 = a[u].y - b[u].y;
        float d2 = a[u].z - b[u].z;
        float d3 = a[u].w - b[u].w;
        accA = fmaf(d0, d0, accA);
        accA = fmaf(d1, d1, accA);
        accB = fmaf(d2, d2, accB);
        accB = fmaf(d3, d3, accB);
    }
    float acc = fmaf(wA, accA, wB * accB);

    // wave (64-lane) reduction
    #pragma unroll
    for (int off = 32; off > 0; off >>= 1)
        acc += __shfl_down(acc, off, 64);

    __shared__ float s_part[4];
    __shared__ int s_last;
    const int wave = threadIdx.x >> 6;
    const int lane = threadIdx.x & 63;
    if (lane == 0) s_part[wave] = acc;
    __syncthreads();
    if (threadIdx.x == 0) {
        float p = s_part[0] + s_part[1] + s_part[2] + s_part[3];
        partials[blockIdx.x] = p;
        __threadfence();                       // make partial visible device-wide
        unsigned int old = atomicAdd(counter, 1u);
        s_last = (old == NBLOCKS - 1) ? 1 : 0; // exactly one block is last
    }
    __syncthreads();

    if (s_last) {
        __threadfence();                       // acquire: all partials visible
        float acc2 = 0.0f;
        #pragma unroll
        for (int k = 0; k < NBLOCKS / 256; ++k)
            acc2 += partials[threadIdx.x + k * 256];   // fixed order: deterministic
        #pragma unroll
        for (int off = 32; off > 0; off >>= 1)
            acc2 += __shfl_down(acc2, off, 64);
        if (lane == 0) s_part[wave] = acc2;
        __syncthreads();
        if (threadIdx.x == 0)
            out[0] = (s_part[0] + s_part[1] + s_part[2] + s_part[3]) * scale;
    }
}

extern "C" void kernel_launch(void* const* d_in, const int* in_sizes, int n_in,
                              void* d_out, int out_size, void* d_ws, size_t ws_size,
                              hipStream_t stream) {
    const float* traj1      = (const float*)d_in[0];
    const float* traj2      = (const float*)d_in[1];
    const float* grid_table = (const float*)d_in[2];
    float* out = (float*)d_out;

    float* partials      = (float*)d_ws;
    unsigned int* counter = (unsigned int*)(partials + NBLOCKS);

    hipMemsetAsync(counter, 0, sizeof(unsigned int), stream);

    const float scale = 1.0f / (float)(B_LEN * T_LEN * D_LEN);
    fused_loss_kernel<<<NBLOCKS, 256, 0, stream>>>(
        (const float4*)traj1, (const float4*)traj2, traj2, grid_table,
        partials, counter, out, scale);
}

// Round 4
// 42.657 us; speedup vs baseline: 2.2710x; 2.2710x over previous
//
#include <hip/hip_runtime.h>

#define GRID_N 100
#define T_LEN 2048
#define B_LEN 4096
#define D_LEN 2
#define NBLOCKS 2048
#define NTHREADS (NBLOCKS * 256)      // 524288
#define UNROLL 8
// n4 = B*T*D/4 = 4,194,304 = NTHREADS * UNROLL exactly (no tail)

// fixed-point: partials scaled by 2^20; output scale = 2^-20 / 2^24 = 2^-44
#define FIX_SCALE 1048576.0
#define OUT_SCALE 5.6843418860808015e-14   // 2^-44
#define CNT_SHIFT 52
#define SUM_MASK ((1ULL << CNT_SHIFT) - 1ULL)

__device__ __forceinline__ float w2_at(const float* __restrict__ traj2,
                                       const float* __restrict__ gt, int t) {
    float lat = traj2[2 * t + 0];
    float lon = traj2[2 * t + 1];
    int lat_g = (int)floorf((lat + 1.0f) * 50.0f);
    lat_g = min(max(lat_g, 0), GRID_N - 1);
    int lon_g = (int)floorf((lon + 1.0f) * 50.0f);
    lon_g = min(max(lon_g, 0), GRID_N - 1);
    return gt[lat_g * GRID_N + lon_g] * 0.0001f + 1.0f;
}

__global__ void __launch_bounds__(256) fused_loss_kernel(
        const float4* __restrict__ t1,
        const float4* __restrict__ t2,
        const float* __restrict__ traj2s,
        const float* __restrict__ grid_table,
        unsigned long long* __restrict__ total,
        float* __restrict__ out) {
    const int tid = blockIdx.x * 256 + threadIdx.x;

    // Bulk load phase first: 16 independent float4 streaming loads in flight.
    float4 a[UNROLL], b[UNROLL];
    #pragma unroll
    for (int u = 0; u < UNROLL; ++u) {
        int j = tid + u * NTHREADS;
        a[u] = t1[j];
        b[u] = t2[j];
    }

    // Weight gather (dependent chain traj2 -> idx -> table) overlaps the
    // streaming-load latency above. t0 constant across unrolls since
    // NTHREADS % 1024 == 0.
    const int t0 = 2 * (tid & (T_LEN * D_LEN / 4 - 1));
    const float wA = w2_at(traj2s, grid_table, t0);
    const float wB = w2_at(traj2s, grid_table, t0 + 1);

    float accA = 0.0f, accB = 0.0f;
    #pragma unroll
    for (int u = 0; u < UNROLL; ++u) {
        float d0 = a[u].x - b[u].x;
        float d1 = a[u].y - b[u].y;
        float d2 = a[u].z - b[u].z;
        float d3 = a[u].w - b[u].w;
        accA = fmaf(d0, d0, accA);
        accA = fmaf(d1, d1, accA);
        accB = fmaf(d2, d2, accB);
        accB = fmaf(d3, d3, accB);
    }
    float acc = fmaf(wA, accA, wB * accB);

    // wave (64-lane) reduction
    #pragma unroll
    for (int off = 32; off > 0; off >>= 1)
        acc += __shfl_down(acc, off, 64);

    __shared__ float s_part[4];
    const int wave = threadIdx.x >> 6;
    const int lane = threadIdx.x & 63;
    if (lane == 0) s_part[wave] = acc;
    __syncthreads();

    if (threadIdx.x == 0) {
        float p = s_part[0] + s_part[1] + s_part[2] + s_part[3];
        // fixed-point partial: integer atomics are exactly commutative ->
        // bitwise-deterministic total, no fence, no second kernel.
        unsigned long long q =
            (unsigned long long)(long long)((double)p * FIX_SCALE + 0.5);
        unsigned long long old = atomicAdd(total, q + (1ULL << CNT_SHIFT));
        if ((old >> CNT_SHIFT) == (unsigned long long)(NBLOCKS - 1)) {
            unsigned long long sum = (old & SUM_MASK) + q;
            out[0] = (float)((double)sum * OUT_SCALE);
        }
    }
}

extern "C" void kernel_launch(void* const* d_in, const int* in_sizes, int n_in,
                              void* d_out, int out_size, void* d_ws, size_t ws_size,
                              hipStream_t stream) {
    const float* traj1      = (const float*)d_in[0];
    const float* traj2      = (const float*)d_in[1];
    const float* grid_table = (const float*)d_in[2];
    float* out = (float*)d_out;

    unsigned long long* total = (unsigned long long*)d_ws;

    hipMemsetAsync(total, 0, sizeof(unsigned long long), stream);

    fused_loss_kernel<<<NBLOCKS, 256, 0, stream>>>(
        (const float4*)traj1, (const float4*)traj2, traj2, grid_table,
        total, out);
}

// Round 5
// 26.140 us; speedup vs baseline: 3.7061x; 1.6319x over previous
//
#include <hip/hip_runtime.h>

#define GRID_N 100
#define T_LEN 2048
#define B_LEN 4096
#define D_LEN 2
#define NBLOCKS 2048
#define NTHREADS (NBLOCKS * 256)      // 524288
#define UNROLL 8
// n4 = B*T*D/4 = 4,194,304 = NTHREADS * UNROLL exactly (no tail)

__device__ __forceinline__ float w2_at(const float* __restrict__ traj2,
                                       const float* __restrict__ gt, int t) {
    float lat = traj2[2 * t + 0];
    float lon = traj2[2 * t + 1];
    int lat_g = (int)floorf((lat + 1.0f) * 50.0f);
    lat_g = min(max(lat_g, 0), GRID_N - 1);
    int lon_g = (int)floorf((lon + 1.0f) * 50.0f);
    lon_g = min(max(lon_g, 0), GRID_N - 1);
    return gt[lat_g * GRID_N + lon_g] * 0.0001f + 1.0f;
}

__global__ void __launch_bounds__(256) main_reduce_kernel(
        const float4* __restrict__ t1,
        const float4* __restrict__ t2,
        const float* __restrict__ traj2s,
        const float* __restrict__ grid_table,
        float* __restrict__ partials) {
    const int tid = blockIdx.x * 256 + threadIdx.x;

    // Load phase: 16 independent float4 loads in flight
    float4 a[UNROLL], b[UNROLL];
    #pragma unroll
    for (int u = 0; u < UNROLL; ++u) {
        int j = tid + u * NTHREADS;
        a[u] = t1[j];
        b[u] = t2[j];
    }

    // This thread's two time indices (constant across all unrolls since
    // NTHREADS % 1024 == 0): t0 = 2*(tid & 1023), covering (t0, t0+1).
    const int t0 = 2 * (tid & (T_LEN * D_LEN / 4 - 1));
    float wA = w2_at(traj2s, grid_table, t0);
    float wB = w2_at(traj2s, grid_table, t0 + 1);

    float accA = 0.0f, accB = 0.0f;
    #pragma unroll
    for (int u = 0; u < UNROLL; ++u) {
        float d0 = a[u].x - b[u].x;
        float d1 = a[u].y - b[u].y;
        float d2 = a[u].z - b[u].z;
        float d3 = a[u].w - b[u].w;
        accA = fmaf(d0, d0, accA);
        accA = fmaf(d1, d1, accA);
        accB = fmaf(d2, d2, accB);
        accB = fmaf(d3, d3, accB);
    }
    float acc = fmaf(wA, accA, wB * accB);

    // wave (64-lane) reduction
    #pragma unroll
    for (int off = 32; off > 0; off >>= 1)
        acc += __shfl_down(acc, off, 64);

    __shared__ float s_part[4];
    int wave = threadIdx.x >> 6;
    int lane = threadIdx.x & 63;
    if (lane == 0) s_part[wave] = acc;
    __syncthreads();
    if (threadIdx.x == 0)
        partials[blockIdx.x] = s_part[0] + s_part[1] + s_part[2] + s_part[3];
}

// Single-wave final reduce: no LDS, no barrier, 32 unrolled reads + 6 shuffles.
__global__ void __launch_bounds__(64) final_reduce_kernel(
        const float* __restrict__ partials,
        float* __restrict__ out, float scale) {
    float acc = 0.0f;
    #pragma unroll
    for (int k = 0; k < NBLOCKS / 64; ++k)
        acc += partials[threadIdx.x + k * 64];
    #pragma unroll
    for (int off = 32; off > 0; off >>= 1)
        acc += __shfl_down(acc, off, 64);
    if (threadIdx.x == 0)
        out[0] = acc * scale;
}

extern "C" void kernel_launch(void* const* d_in, const int* in_sizes, int n_in,
                              void* d_out, int out_size, void* d_ws, size_t ws_size,
                              hipStream_t stream) {
    const float* traj1      = (const float*)d_in[0];
    const float* traj2      = (const float*)d_in[1];
    const float* grid_table = (const float*)d_in[2];
    float* out = (float*)d_out;

    float* partials = (float*)d_ws;

    main_reduce_kernel<<<NBLOCKS, 256, 0, stream>>>(
        (const float4*)traj1, (const float4*)traj2, traj2, grid_table, partials);

    const float scale = 1.0f / (float)(B_LEN * T_LEN * D_LEN);
    final_reduce_kernel<<<1, 64, 0, stream>>>(partials, out, scale);
}